// Round 4
// baseline (8124.869 us; speedup 1.0000x reference)
//
#include <hip/hip_runtime.h>
#include <hip/hip_bf16.h>

#define B_ 256
#define T_ 500
#define I_ 256
#define H_ 512
#define G_ 2048   // 4*H
#define O_ 100

// ---- persistent-kernel geometry ----
// 256 blocks x 128 threads (2 waves). Group g = bid & 7 owns 32 batch rows
// (wave0: rows 0-15, wave1: rows 16-31 of the group). Cell chunk cc = bid >> 3
// owns 16 cells (x4 gates = 64 gate-cells, 64 KB LDS). 32 blocks per group.
// bid%8 == g -> whole group lands on one XCD under round-robin (perf only;
// correctness uses agent-scope atomics/fences).
#define NGRP 8
#define GRP_BLKS 32
#define CNT_STRIDE 32   // uints -> 128 B per group counter

typedef __attribute__((ext_vector_type(8))) short short8;
typedef __attribute__((ext_vector_type(4))) float f32x4;

// ---- workspace layout (bytes) ----  (fallback path uses all; persistent uses H0/H1/CNT)
#define WHB_OFF  0u                              // Wh bf16 [2048][512]   2 MB
#define WXB_OFF  (G_*H_*2u)                      // Wx bf16 [2048][256]   1 MB
#define BSUM_OFF (WXB_OFF + G_*I_*2u)            // bx+bh f32 [2048]      8 KB
#define H0_OFF   (BSUM_OFF + G_*4u)              // h buf0 bf16 [256][512] 256 KB
#define H1_OFF   (H0_OFF + B_*H_*2u)             // h buf1 bf16            256 KB
#define C_OFF    (H1_OFF + B_*H_*2u)             // c f32 (fallback)       512 KB
#define HT_OFF   (C_OFF + B_*H_*4u)              // final h f32 (fallback) 512 KB
#define CNT_OFF  (HT_OFF + B_*H_*4u)             // barrier counters       1 KB
// total ~4.52 MB

__device__ __forceinline__ float sigm(float v) { return 1.0f / (1.0f + __expf(-v)); }
__device__ __forceinline__ float tanh_fast(float v) { return 2.0f / (1.0f + __expf(-2.0f * v)) - 1.0f; }

__device__ __forceinline__ short f2bf(float f) {
  union { __hip_bfloat16 h; unsigned short u; } cv;
  cv.h = __float2bfloat16(f);
  return (short)cv.u;
}
__device__ __forceinline__ short8 cvt8(float4 a, float4 b) {
  short8 s;
  s[0]=f2bf(a.x); s[1]=f2bf(a.y); s[2]=f2bf(a.z); s[3]=f2bf(a.w);
  s[4]=f2bf(b.x); s[5]=f2bf(b.y); s[6]=f2bf(b.z); s[7]=f2bf(b.w);
  return s;
}

// ================= persistent cooperative kernel =================
__global__ __launch_bounds__(128, 1)
void lstm_persist(const float* __restrict__ x, const float* __restrict__ Wx,
                  const float* __restrict__ bx, const float* __restrict__ Wh,
                  const float* __restrict__ bh,
                  unsigned short* __restrict__ hbuf0, unsigned short* __restrict__ hbuf1,
                  unsigned int* __restrict__ cnt)
{
  __shared__ short whlds[32768];            // 64 KB: [64 gate-cells][512] bf16, XOR-swizzled
  char* ldsb = (char*)whlds;

  const int tid = threadIdx.x;
  const int l   = tid & 63;
  const int w   = tid >> 6;                 // wave 0/1 -> batch rows 0-15 / 16-31 of group
  const int g   = blockIdx.x & 7;           // batch group (32 rows)
  const int cc  = blockIdx.x >> 3;          // cell chunk (16 cells)
  const int rbase = g * 32 + w * 16;
  const int cbase = cc * 16;
  const int r   = l & 15;                   // MFMA row/col selector
  const int u   = l >> 4;                   // 0..3
  const int rx  = (r & 7) << 4;             // read-side XOR

  // ---- init: Wh slice -> LDS (f32->bf16, XOR-swizzled rows) ----
  {
    const int gc = tid >> 1;                // LDS row 0..63 (= q*16 + cell-in-chunk)
    const int kh = (tid & 1) * 256;         // half of K
    const int q = gc >> 4, li = gc & 15;
    const float* src = Wh + ((size_t)(q * H_ + cbase + li)) * H_ + kh;
    const int rowb = gc * (H_ * 2);
    const int wxz = (gc & 7) << 4;
    for (int k = 0; k < 256; k += 8) {
      float4 f0 = *(const float4*)(src + k);
      float4 f1 = *(const float4*)(src + k + 4);
      int byte = (rowb + (kh + k) * 2) ^ wxz;
      *(short8*)(ldsb + byte) = cvt8(f0, f1);
    }
  }

  // ---- init: Wx slice -> 128 VGPRs (same cells for both waves) ----
  short8 wxr[4][8];
  #pragma unroll
  for (int q = 0; q < 4; ++q)
    #pragma unroll
    for (int kc = 0; kc < 8; ++kc) {
      const float* p = Wx + ((size_t)(q * H_ + cbase + r)) * I_ + kc * 32 + u * 8;
      wxr[q][kc] = cvt8(*(const float4*)p, *(const float4*)(p + 4));
    }

  float bsum[4];
  #pragma unroll
  for (int q = 0; q < 4; ++q)
    bsum[q] = bx[q * H_ + cbase + r] + bh[q * H_ + cbase + r];

  float creg[4] = {0.f, 0.f, 0.f, 0.f};

  __syncthreads();                          // LDS weights ready

  // ---- x prefetch for t=0 ----
  short8 xf[8];
  #pragma unroll
  for (int kc = 0; kc < 8; ++kc) {
    const float* p = x + ((size_t)(rbase + r) * T_ + 0) * I_ + kc * 32 + u * 8;
    xf[kc] = cvt8(*(const float4*)p, *(const float4*)(p + 4));
  }

  unsigned int* mycnt = cnt + g * CNT_STRIDE;

  for (int t = 0; t < T_; ++t) {
    const unsigned short* hin = (t & 1) ? hbuf1 : hbuf0;
    unsigned short* hout      = (t & 1) ? hbuf0 : hbuf1;

    f32x4 acc[4];
    #pragma unroll
    for (int q = 0; q < 4; ++q) acc[q] = (f32x4){0.f, 0.f, 0.f, 0.f};

    // x-part MFMAs: operands in regs, no dependence on h_{t-1}; runs while
    // the rest of the group is still storing/propagating h.
    #pragma unroll
    for (int kc = 0; kc < 8; ++kc)
      #pragma unroll
      for (int q = 0; q < 4; ++q)
        acc[q] = __builtin_amdgcn_mfma_f32_16x16x32_bf16(xf[kc], wxr[q][kc], acc[q], 0, 0, 0);

    // ---- wait: h_{t-1} visible (skip at t=0; zeros from memset) ----
    if (t > 0) {
      if (tid == 0) {
        const unsigned int target = (unsigned int)GRP_BLKS * (unsigned int)t;
        while (__hip_atomic_load(mycnt, __ATOMIC_RELAXED, __HIP_MEMORY_SCOPE_AGENT) < target)
          __builtin_amdgcn_s_sleep(1);
      }
      __syncthreads();                                        // hold both waves
      __builtin_amdgcn_fence(__ATOMIC_ACQUIRE, "agent");      // invalidate stale caches
    }

    // ---- h-part: A frags from global h, B frags from LDS ----
    const unsigned short* hp = hin + (size_t)(rbase + r) * H_ + u * 8;
    #pragma unroll
    for (int kc = 0; kc < 16; ++kc) {
      short8 a = *(const short8*)(hp + kc * 32);
      #pragma unroll
      for (int q = 0; q < 4; ++q) {
        int byte = ((q * 16 + r) * (H_ * 2) + kc * 64 + u * 16) ^ rx;
        short8 b = *(const short8*)(ldsb + byte);
        acc[q] = __builtin_amdgcn_mfma_f32_16x16x32_bf16(a, b, acc[q], 0, 0, 0);
      }
    }

    // ---- cell update: lane holds i,f,g,o for (row = rbase + u*4 + j, cell) ----
    #pragma unroll
    for (int j = 0; j < 4; ++j) {
      float ig = sigm(acc[0][j] + bsum[0]);
      float fg = sigm(acc[1][j] + bsum[1]);
      float gg = tanh_fast(acc[2][j] + bsum[2]);
      float og = sigm(acc[3][j] + bsum[3]);
      float cn = creg[j] * fg + ig * gg;
      creg[j] = cn;
      float hn = og * tanh_fast(cn);
      hout[(size_t)(rbase + u * 4 + j) * H_ + cbase + r] = (unsigned short)f2bf(hn);
    }

    // ---- signal: drain both waves' stores, then release-add ----
    if (t + 1 < T_) {
      __syncthreads();                       // implicit vmcnt(0) drains h stores to L2
      if (tid == 0)
        __hip_atomic_fetch_add(mycnt, 1u, __ATOMIC_RELEASE, __HIP_MEMORY_SCOPE_AGENT);
      // prefetch x_{t+1} AFTER the signal: load latency hides under the spin
      #pragma unroll
      for (int kc = 0; kc < 8; ++kc) {
        const float* p = x + ((size_t)(rbase + r) * T_ + (t + 1)) * I_ + kc * 32 + u * 8;
        xf[kc] = cvt8(*(const float4*)p, *(const float4*)(p + 4));
      }
    }
  }
}

// ================= fallback path (round-1, known-pass) =================
__global__ void cast_kernel(const float* __restrict__ Wh, const float* __restrict__ Wx,
                            const float* __restrict__ bx, const float* __restrict__ bh,
                            short* __restrict__ Whb, short* __restrict__ Wxb,
                            float* __restrict__ bsum) {
  int idx = blockIdx.x * 256 + threadIdx.x;
  if (idx < G_ * H_) Whb[idx] = f2bf(Wh[idx]);
  if (idx < G_ * I_) Wxb[idx] = f2bf(Wx[idx]);
  if (idx < G_)      bsum[idx] = bx[idx] + bh[idx];
}

__global__ __launch_bounds__(128)
void lstm_step(const float* __restrict__ x, int t,
               const short* __restrict__ Whb, const short* __restrict__ Wxb,
               const float* __restrict__ bsum,
               const short* __restrict__ h_in,
               unsigned short* __restrict__ h_out,
               float* __restrict__ c,
               float* __restrict__ hT) {
  const int lane = threadIdx.x & 63;
  const int w    = threadIdx.x >> 6;
  const int r    = lane & 15;
  const int ko   = (lane >> 4) << 3;
  const int brow = blockIdx.y * 32 + w * 16;
  const int cbase = blockIdx.x * 16;

  f32x4 acc[4];
  #pragma unroll
  for (int q = 0; q < 4; ++q) acc[q] = (f32x4){0.f, 0.f, 0.f, 0.f};

  const short* ha = h_in + (size_t)(brow + r) * H_ + ko;
  #pragma unroll 4
  for (int kk = 0; kk < H_; kk += 32) {
    short8 a = *reinterpret_cast<const short8*>(ha + kk);
    #pragma unroll
    for (int q = 0; q < 4; ++q) {
      const short* bp = Whb + (size_t)(q * H_ + cbase + r) * H_ + kk + ko;
      short8 b = *reinterpret_cast<const short8*>(bp);
      acc[q] = __builtin_amdgcn_mfma_f32_16x16x32_bf16(a, b, acc[q], 0, 0, 0);
    }
  }

  const float* xrow = x + ((size_t)(brow + r) * T_ + t) * I_ + ko;
  #pragma unroll 2
  for (int kk = 0; kk < I_; kk += 32) {
    float4 x0 = *reinterpret_cast<const float4*>(xrow + kk);
    float4 x1 = *reinterpret_cast<const float4*>(xrow + kk + 4);
    short8 a = cvt8(x0, x1);
    #pragma unroll
    for (int q = 0; q < 4; ++q) {
      const short* bp = Wxb + (size_t)(q * H_ + cbase + r) * I_ + kk + ko;
      short8 b = *reinterpret_cast<const short8*>(bp);
      acc[q] = __builtin_amdgcn_mfma_f32_16x16x32_bf16(a, b, acc[q], 0, 0, 0);
    }
  }

  const int cell = cbase + r;
  #pragma unroll
  for (int j = 0; j < 4; ++j) {
    const int row = brow + ((lane >> 4) << 2) + j;
    const size_t ci = (size_t)row * H_ + cell;
    float ig = sigm(acc[0][j] + bsum[0 * H_ + cell]);
    float fg = sigm(acc[1][j] + bsum[1 * H_ + cell]);
    float gg = tanh_fast(acc[2][j] + bsum[2 * H_ + cell]);
    float og = sigm(acc[3][j] + bsum[3 * H_ + cell]);
    float cn = c[ci] * fg + ig * gg;
    c[ci] = cn;
    float hn = og * tanh_fast(cn);
    h_out[ci] = (unsigned short)f2bf(hn);
    if (hT) hT[ci] = hn;
  }
}

__global__ __launch_bounds__(128)
void fc_f32(const float* __restrict__ hT, const float* __restrict__ Wfc,
            const float* __restrict__ bfc, float* __restrict__ out) {
  int b = blockIdx.x;
  int o = threadIdx.x;
  if (o >= O_) return;
  const float* hr = hT + (size_t)b * H_;
  const float* wr = Wfc + (size_t)o * H_;
  float s = 0.f;
  #pragma unroll 4
  for (int k = 0; k < H_; k += 4) {
    float4 hv = *reinterpret_cast<const float4*>(hr + k);
    float4 wv = *reinterpret_cast<const float4*>(wr + k);
    s += hv.x * wv.x + hv.y * wv.y + hv.z * wv.z + hv.w * wv.w;
  }
  out[b * O_ + o] = s + bfc[o];
}

__global__ __launch_bounds__(128)
void fc_bf16(const unsigned short* __restrict__ h, const float* __restrict__ Wfc,
             const float* __restrict__ bfc, float* __restrict__ out) {
  int b = blockIdx.x;
  int o = threadIdx.x;
  if (o >= O_) return;
  const unsigned short* hr = h + (size_t)b * H_;
  const float* wr = Wfc + (size_t)o * H_;
  float s = 0.f;
  #pragma unroll 4
  for (int k = 0; k < H_; k += 8) {
    short8 hv = *(const short8*)(hr + k);
    #pragma unroll
    for (int j = 0; j < 8; ++j) {
      union { unsigned int uu; float f; } cv;
      cv.uu = ((unsigned int)(unsigned short)hv[j]) << 16;
      s += cv.f * wr[k + j];
    }
  }
  out[b * O_ + o] = s + bfc[o];
}

extern "C" void kernel_launch(void* const* d_in, const int* in_sizes, int n_in,
                              void* d_out, int out_size, void* d_ws, size_t ws_size,
                              hipStream_t stream) {
  const float* x   = (const float*)d_in[0];
  const float* Wx  = (const float*)d_in[1];
  const float* bx  = (const float*)d_in[2];
  const float* Wh  = (const float*)d_in[3];
  const float* bh  = (const float*)d_in[4];
  const float* Wfc = (const float*)d_in[5];
  const float* bfc = (const float*)d_in[6];
  float* out = (float*)d_out;
  char* ws = (char*)d_ws;

  unsigned short* h0  = (unsigned short*)(ws + H0_OFF);
  unsigned short* h1  = (unsigned short*)(ws + H1_OFF);
  unsigned int*   cnt = (unsigned int*)(ws + CNT_OFF);

  hipMemsetAsync(ws + H0_OFF, 0, B_ * H_ * 2, stream);               // h0 = 0
  hipMemsetAsync(ws + C_OFF,  0, B_ * H_ * 4, stream);               // c = 0 (fallback)
  hipMemsetAsync(ws + CNT_OFF, 0, NGRP * CNT_STRIDE * 4, stream);    // barrier counters

  void* args[] = {(void*)&x, (void*)&Wx, (void*)&bx, (void*)&Wh, (void*)&bh,
                  (void*)&h0, (void*)&h1, (void*)&cnt};
  hipError_t e = hipLaunchCooperativeKernel((const void*)lstm_persist,
                                            dim3(NGRP * GRP_BLKS), dim3(128), args, 0, stream);
  if (e == hipSuccess) {
    fc_bf16<<<dim3(B_), dim3(128), 0, stream>>>(h0, Wfc, bfc, out);
  } else {
    // Multi-launch fallback: correct and hang-free (no inter-block spin).
    (void)hipGetLastError();   // clear error state from the rejected coop launch
    short* Whb  = (short*)(ws + WHB_OFF);
    short* Wxb  = (short*)(ws + WXB_OFF);
    float* bsum = (float*)(ws + BSUM_OFF);
    float* cbuf = (float*)(ws + C_OFF);
    float* hT   = (float*)(ws + HT_OFF);
    cast_kernel<<<(G_ * H_ + 255) / 256, 256, 0, stream>>>(Wh, Wx, bx, bh, Whb, Wxb, bsum);
    for (int t = 0; t < T_; ++t) {
      const short* hin = (short*)((t & 1) ? h1 : h0);
      unsigned short* hout = (t & 1) ? h0 : h1;
      lstm_step<<<dim3(32, 8), 128, 0, stream>>>(x, t, Whb, Wxb, bsum, hin, hout, cbuf,
                                                 (t == T_ - 1) ? hT : nullptr);
    }
    fc_f32<<<dim3(B_), dim3(128), 0, stream>>>(hT, Wfc, bfc, out);
  }
}